// Round 21
// baseline (159.961 us; speedup 1.0000x reference)
//
#include <hip/hip_runtime.h>
#include <math.h>
#include <stdint.h>

// Problem constants
#define NB 4
#define NC 128
#define NP 4096
#define KNN 10

// ---------------- ws layout (float-slot offsets) ----------------
// Xcat (bf16 u16) : [B][N][512]   @ 0         (16MB)
// KNN scratch     : @ 4194304  (candd 1310720, tq 16384, pts4 65536 slots)
// Ub1  (bf16 u16) : [B][N][128]   @ 5586944
// Ub2  (bf16 u16) : [B][N][256]   @ 6635520
// Sbuf (bf16 u16) : [B][N][256]   @ 12582912  (S = u + maxV)
// Y3   (f32)      : [B][N][128]   @ 14680064
// idx  (i32)      : [B][N][10]    @ 16777216
// W1cat (bf16)    : [256][128]    @ 16941056
// W2cat (bf16)    : [512][128]    @ 16957440
// W3b  (bf16)     : [128][512]    @ 16990208
// stats (f32)     : [8192]        @ 17022976
// Vb1  (bf16 u16) : [B][N][128]   @ 17031168
// Vb2  (bf16 u16) : [B][N][256]   @ 18079744

__device__ __forceinline__ uint16_t f2bf(float f) {
  uint32_t u = __float_as_uint(f);
  u += 0x7fffu + ((u >> 16) & 1u);      // RNE
  return (uint16_t)(u >> 16);
}
__device__ __forceinline__ float bf2f(uint16_t h) {
  return __uint_as_float(((uint32_t)h) << 16);
}

__device__ __forceinline__ void async16(const void* g, void* l) {
  __builtin_amdgcn_global_load_lds(
      (const __attribute__((address_space(1))) unsigned int*)g,
      (__attribute__((address_space(3))) unsigned int*)l,
      16, 0, 0);
}

// float -> order-preserving uint32 (all finite values)
__device__ __forceinline__ uint32_t fsort(float f) {
  uint32_t u = __float_as_uint(f);
  return (u & 0x80000000u) ? ~u : (u | 0x80000000u);
}
__device__ __forceinline__ float funsort(uint32_t k) {
  uint32_t u = (k & 0x80000000u) ? (k & 0x7fffffffu) : ~k;
  return __uint_as_float(u);
}

typedef __bf16 bf16x8 __attribute__((ext_vector_type(8)));
typedef float f32x4 __attribute__((ext_vector_type(4)));

// prep (blocks >= 2048) + feature transpose (blocks 0..2047), fused.
__global__ void k_prep(const float* __restrict__ W1, const float* __restrict__ W2,
                       const float* __restrict__ W3, const float* __restrict__ coords,
                       const float* __restrict__ feat,
                       uint16_t* __restrict__ Xcat,
                       uint16_t* __restrict__ W1cat, uint16_t* __restrict__ W2cat,
                       uint16_t* __restrict__ W3b,
                       float* __restrict__ stats, float4* __restrict__ pts4) {
  __shared__ float tile[32][33];
  int bid = blockIdx.x;
  if (bid < 2048) {               // transpose: feat [B][128][4096] -> Xcat bf16
    int b = bid >> 9;
    int r = bid & 511;
    int n0 = (r >> 2) << 5;
    int c0 = (r & 3) << 5;
    int tx = threadIdx.x & 31, ty = threadIdx.x >> 5;
#pragma unroll
    for (int i = 0; i < 4; i++) {
      int c = c0 + ty + i * 8;
      tile[ty + i * 8][tx] = feat[(b * 128 + c) * 4096 + n0 + tx];
    }
    __syncthreads();
#pragma unroll
    for (int i = 0; i < 4; i++) {
      int n = n0 + ty + i * 8;
      Xcat[((b * 4096 + n) * 512) + c0 + tx] = f2bf(tile[tx][ty + i * 8]);
    }
    return;
  }
  int t = (bid - 2048) * 256 + threadIdx.x;
  if (t < 32768) {
    int o = t >> 7, c = t & 127;
    float v;
    if (o < 128) v = W1[o * 256 + c] - W1[o * 256 + 128 + c];     // A1 = W1a - W1b
    else         v = W1[(o - 128) * 256 + 128 + c];               // B1 = W1b
    W1cat[t] = f2bf(v);
  } else if (t < 98304) {
    int t2 = t - 32768;
    int o = t2 >> 7, c = t2 & 127;
    float v;
    if (o < 256) v = W2[o * 256 + c] - W2[o * 256 + 128 + c];     // A2
    else         v = W2[(o - 256) * 256 + 128 + c];               // B2
    W2cat[t2] = f2bf(v);
  } else if (t < 163840) {
    int t2 = t - 98304;
    W3b[t2] = f2bf(W3[t2]);
  } else if (t < 163840 + 8192) {
    stats[t - 163840] = 0.f;
  } else if (t < 163840 + 8192 + 16384) {
    int t2 = t - 163840 - 8192;
    int b = t2 >> 12, n = t2 & 4095;
    const float* cb = coords + b * 12288;
    float x = cb[n], y = cb[4096 + n], z = cb[8192 + n];
    float w = fmaf(x, x, fmaf(y, y, z * z));
    pts4[t2] = make_float4(x, y, z, w);
  }
}

// ---------------- KNN: exact subsampled-threshold scheme ----------------
// d = fmaf(-2, dot, q.w + p.w), dot = fmaf(qx,px, fmaf(qy,py, qz*pz)):
// the SAME chain in thr and in cf's hit-branch recompute (bit-identical).
__global__ void k_knn_thr(const float4* __restrict__ pts4, float* __restrict__ candd) {
  int L = blockIdx.x;             // 512 = b(4) x qb(16) x ch(8)
  int ch = L & 7;
  int qb = (L >> 3) & 15;
  int b = L >> 7;
  int m0 = ch << 7;               // subset points ch*128 .. +127  (all < 1024)
  const float4* pb = pts4 + b * 4096;
  int t = threadIdx.x;
  int q = (qb << 8) + t;
  float4 qp = pb[q];
  float d10[10];
#pragma unroll
  for (int i = 0; i < 10; i++) d10[i] = 1e30f;
#pragma unroll 2
  for (int mm = 0; mm < 128; mm++) {
    int m = m0 + mm;
    float4 p = pb[m];                     // wave-uniform -> broadcast
    float dot = fmaf(qp.x, p.x, fmaf(qp.y, p.y, qp.z * p.z));
    float s = qp.w + p.w;
    float d = fmaf(-2.f, dot, s);
    d = (m == q) ? 1e30f : d;             // self-exclusion
    if (d < d10[9]) {
      float carry = d;
#pragma unroll
      for (int i = 0; i < 10; i++) {
        float lo = fminf(d10[i], carry);
        carry = fmaxf(d10[i], carry);
        d10[i] = lo;
      }
    }
  }
  int row = b * 4096 + q;
#pragma unroll
  for (int i = 0; i < 10; i++) candd[row * 80 + ch * 10 + i] = d10[i];
}

__global__ void k_knn_merge(const float* __restrict__ candd, float* __restrict__ tq) {
  int gw = blockIdx.x * 4 + (threadIdx.x >> 6);   // 4096 blocks -> 16384 waves
  int l = threadIdx.x & 63;
  const float* cp = candd + (size_t)gw * 80;
  uint32_t k0 = fsort(cp[l]);
  uint32_t k1 = (l < 16) ? fsort(cp[64 + l]) : 0xFFFFFFFFu;
  uint32_t g = 0;
#pragma unroll
  for (int it = 0; it < 10; it++) {
    uint32_t m = k0 < k1 ? k0 : k1;
#pragma unroll
    for (int s = 1; s < 64; s <<= 1) {
      uint32_t o = __shfl_xor(m, s);
      m = o < m ? o : m;
    }
    g = m;
    if (it < 9) {
      if (k0 == m) k0 = 0xFFFFFFFFu;
      else if (k1 == m) k1 = 0xFFFFFFFFu;
    }
  }
  if (l == 0) tq[gw] = funsort(g);
}

// Phase C+D fused: register-query/partitioned-point scan (r16) with
// (d, idx) stored in LDS at hit time (exact chain recomputed in the rare
// hit branch), then u32-key wave selection with emit-during-extract:
// 10x { 6-step shfl32 min butterfly + ballot; winner lane (min-idx on
// ties, matching the reference's stable tie-break) emits its idx and
// removes ONE instance }. Output set == lexicographic (d,idx) top-10.
#define CFCAP 112
#define DMARGIN 1e-3f
__global__ __launch_bounds__(256) void k_knn_cf(
    const float4* __restrict__ pts4, const float* __restrict__ tq,
    int* __restrict__ idxout) {
  __shared__ float cdd[8 * CFCAP];           // 3.5 KB
  __shared__ int candi[8 * CFCAP];           // 3.5 KB
  __shared__ int ccnt[8];
  int blk = blockIdx.x;           // 2048 = b(4) x qg(512)
  int b = blk >> 9;
  int qg = blk & 511;
  int t = threadIdx.x;
  if (t < 8) ccnt[t] = 0;
  const float4* pb = pts4 + b * 4096;
  int qbase = qg * 8;
  float q2x[8], q2y[8], q2z[8], qw[8], rhs[8];
#pragma unroll
  for (int j = 0; j < 8; j++) {
    float4 qp = pb[qbase + j];
    q2x[j] = -2.f * qp.x; q2y[j] = -2.f * qp.y; q2z[j] = -2.f * qp.z;
    qw[j] = qp.w;
    rhs[j] = tq[b * 4096 + qbase + j] + DMARGIN - qp.w;
  }
  __syncthreads();                // ccnt init visible
#pragma unroll 4
  for (int c = 0; c < 16; c++) {
    float4 p = pb[c * 256 + t];   // coalesced global (L2-resident)
    int m = c * 256 + t;
#pragma unroll
    for (int j = 0; j < 8; j++) {
      float tt = fmaf(q2x[j], p.x, fmaf(q2y[j], p.y, fmaf(q2z[j], p.z, p.w)));
      if (tt <= rhs[j]) {
        // EXACT d, bit-identical chain vs thr (qx == -0.5*(-2*qx) exactly)
        float qx = -0.5f * q2x[j], qy = -0.5f * q2y[j], qz = -0.5f * q2z[j];
        float dot = fmaf(qx, p.x, fmaf(qy, p.y, qz * p.z));
        float d = fmaf(-2.f, dot, qw[j] + p.w);
        int pos = atomicAdd(&ccnt[j], 1);
        if (pos < CFCAP) { cdd[j * CFCAP + pos] = d; candi[j * CFCAP + pos] = m; }
      }
    }
  }
  __syncthreads();
  // selection: 4 waves; wave w handles queries w*2, w*2+1.
  int w = t >> 6;
  int l = t & 63;
  for (int k = 0; k < 2; k++) {
    int qloc = w * 2 + k;
    int q2 = qbase + qloc;
    int c = ccnt[qloc]; c = c < CFCAP ? c : CFCAP;
    float d0 = 1e30f, d1 = 1e30f; int i0 = 0x7fffffff, i1 = 0x7fffffff;
    if (l < c)      { d0 = cdd[qloc * CFCAP + l];      i0 = candi[qloc * CFCAP + l];
                      if (i0 == q2) d0 = 1e30f; }
    if (64 + l < c) { d1 = cdd[qloc * CFCAP + 64 + l]; i1 = candi[qloc * CFCAP + 64 + l];
                      if (i1 == q2) d1 = 1e30f; }
    uint32_t k0 = fsort(d0), k1 = fsort(d1);
    int orow = b * 4096 + q2;
#pragma unroll
    for (int it = 0; it < 10; it++) {
      uint32_t m = k0 < k1 ? k0 : k1;
#pragma unroll
      for (int s = 1; s < 64; s <<= 1) {
        uint32_t o = __shfl_xor(m, s);
        m = o < m ? o : m;
      }
      // local removal candidate: min idx among this lane's matching slots
      int li = 0x7fffffff, ls = -1;
      if (k0 == m) { li = i0; ls = 0; }
      if (k1 == m && i1 < li) { li = i1; ls = 1; }
      unsigned long long bal = __ballot(ls >= 0);
      int winner;
      if (__popcll(bal) == 1) {
        winner = __ffsll(bal) - 1;
      } else {                    // rare tie on d: reference takes min idx
        int mi = (ls >= 0) ? li : 0x7fffffff;
#pragma unroll
        for (int s = 1; s < 64; s <<= 1) {
          int o = __shfl_xor(mi, s);
          mi = o < mi ? o : mi;
        }
        unsigned long long b2 = __ballot(ls >= 0 && li == mi);
        winner = __ffsll(b2) - 1;
      }
      if (l == winner) {
        idxout[orow * 10 + it] = li;
        if (ls == 0) k0 = 0xFFFFFFFFu; else k1 = 0xFFFFFFFFu;
      }
    }
  }
}

// ---------------- bf16 MFMA GEMM (stage 1/2): BM=128, BN=64 ----------------
// [U|V] = X @ W^T; U blocks -> Ub bf16, V blocks -> Vb bf16.
__global__ __launch_bounds__(256) void k_gemm_bf(
    const uint16_t* __restrict__ Xb, int ldx, int xoff,
    const uint16_t* __restrict__ Wb, int ldw, int K,
    uint16_t* __restrict__ Ub, uint16_t* __restrict__ Vb,
    int voff, int uld, int vld) {
  __shared__ __align__(16) uint8_t lds[49152];
  const int t = threadIdx.x;
  const int l = t & 63;
  const int wid = t >> 6;
  const int wr = wid & 1, wc = wid >> 1;
  const int p0 = blockIdx.x * 128;
  const int o0 = blockIdx.y * 64;

  const int rA = l >> 3;
  const int cbp = ((l & 7) ^ rA) << 4;
  const int swl = (l & 7) << 4;

  f32x4 acc[4][2];
#pragma unroll
  for (int mi = 0; mi < 4; mi++)
#pragma unroll
    for (int ni = 0; ni < 2; ni++) acc[mi][ni] = (f32x4)0.f;

  auto stage = [&](int k0, int buf) {
    const uint16_t* Xs_ = Xb + (size_t)p0 * ldx + xoff + k0;
    const uint16_t* Ws_ = Wb + (size_t)o0 * ldw + k0;
#pragma unroll
    for (int cc = 0; cc < 4; cc++) {
      int c = wid * 4 + cc;
      const uint8_t* g = (const uint8_t*)(Xs_ + (size_t)(c * 8 + rA) * ldx) + cbp;
      async16(g, &lds[buf * 16384 + c * 1024]);
    }
#pragma unroll
    for (int cc = 0; cc < 2; cc++) {
      int c = wid * 2 + cc;
      const uint8_t* g = (const uint8_t*)(Ws_ + (size_t)(c * 8 + rA) * ldw) + cbp;
      async16(g, &lds[32768 + buf * 8192 + c * 1024]);
    }
  };

  auto compute = [&](int buf) {
    const uint8_t* Ab = &lds[buf * 16384];
    const uint8_t* Bb = &lds[32768 + buf * 8192];
#pragma unroll
    for (int ks = 0; ks < 2; ks++) {
      int cb = ks * 64 + ((l >> 4) << 4);
      bf16x8 bfr[2];
#pragma unroll
      for (int ni = 0; ni < 2; ni++) {
        int n = wc * 32 + ni * 16 + (l & 15);
        bfr[ni] = *(const bf16x8*)(Bb + n * 128 + (cb ^ swl));
      }
#pragma unroll
      for (int mi = 0; mi < 4; mi++) {
        int m = wr * 64 + mi * 16 + (l & 15);
        bf16x8 afr = *(const bf16x8*)(Ab + m * 128 + (cb ^ swl));
        acc[mi][0] = __builtin_amdgcn_mfma_f32_16x16x32_bf16(afr, bfr[0], acc[mi][0], 0, 0, 0);
        acc[mi][1] = __builtin_amdgcn_mfma_f32_16x16x32_bf16(afr, bfr[1], acc[mi][1], 0, 0, 0);
      }
    }
  };

  const int nsteps = K >> 6;
  stage(0, 0);
  for (int s = 0; s < nsteps; s++) {
    __syncthreads();
    if (s + 1 < nsteps) stage((s + 1) << 6, (s + 1) & 1);
    compute(s & 1);
  }

  const bool isv = (o0 >= voff);  // wave-uniform
#pragma unroll
  for (int mi = 0; mi < 4; mi++)
#pragma unroll
    for (int ni = 0; ni < 2; ni++) {
      int col = o0 + wc * 32 + ni * 16 + (l & 15);
      int row0 = p0 + wr * 64 + mi * 16 + (l >> 4) * 4;
#pragma unroll
      for (int j = 0; j < 4; j++) {
        if (isv) Vb[(size_t)(row0 + j) * vld + (col - voff)] = f2bf(acc[mi][ni][j]);
        else     Ub[(size_t)(row0 + j) * uld + col] = f2bf(acc[mi][ni][j]);
      }
    }
}

// ---------------- gemm3: BM=64, BN=64, f32 out + fused stats ----------------
__global__ __launch_bounds__(256) void k_gemm3(
    const uint16_t* __restrict__ Xb, int ldx,
    const uint16_t* __restrict__ Wb, int ldw,
    float* __restrict__ Y, int ldy, int K,
    float* __restrict__ T1s, float* __restrict__ T2s) {
  __shared__ __align__(16) uint8_t lds[32768];
  const int t = threadIdx.x;
  const int l = t & 63;
  const int wid = t >> 6;         // wc 0..3
  const int p0 = blockIdx.x * 64;
  const int o0 = blockIdx.y * 64;

  const int rA = l >> 3;
  const int cbp = ((l & 7) ^ rA) << 4;
  const int swl = (l & 7) << 4;

  f32x4 acc[4];
#pragma unroll
  for (int mi = 0; mi < 4; mi++) acc[mi] = (f32x4)0.f;

  auto stage = [&](int k0, int buf) {
    const uint16_t* Xs_ = Xb + (size_t)p0 * ldx + k0;
    const uint16_t* Ws_ = Wb + (size_t)o0 * ldw + k0;
#pragma unroll
    for (int cc = 0; cc < 2; cc++) {
      int c = wid * 2 + cc;
      const uint8_t* g = (const uint8_t*)(Xs_ + (size_t)(c * 8 + rA) * ldx) + cbp;
      async16(g, &lds[buf * 16384 + c * 1024]);
    }
#pragma unroll
    for (int cc = 0; cc < 2; cc++) {
      int c = wid * 2 + cc;
      const uint8_t* g = (const uint8_t*)(Ws_ + (size_t)(c * 8 + rA) * ldw) + cbp;
      async16(g, &lds[buf * 16384 + 8192 + c * 1024]);
    }
  };

  auto compute = [&](int buf) {
    const uint8_t* Ab = &lds[buf * 16384];
    const uint8_t* Bb = &lds[buf * 16384 + 8192];
#pragma unroll
    for (int ks = 0; ks < 2; ks++) {
      int cb = ks * 64 + ((l >> 4) << 4);
      int n = wid * 16 + (l & 15);
      bf16x8 bfr = *(const bf16x8*)(Bb + n * 128 + (cb ^ swl));
#pragma unroll
      for (int mi = 0; mi < 4; mi++) {
        int m = mi * 16 + (l & 15);
        bf16x8 afr = *(const bf16x8*)(Ab + m * 128 + (cb ^ swl));
        acc[mi] = __builtin_amdgcn_mfma_f32_16x16x32_bf16(afr, bfr, acc[mi], 0, 0, 0);
      }
    }
  };

  const int nsteps = K >> 6;      // 8
  stage(0, 0);
  for (int s = 0; s < nsteps; s++) {
    __syncthreads();
    if (s + 1 < nsteps) stage((s + 1) << 6, (s + 1) & 1);
    compute(s & 1);
  }

  int col = o0 + wid * 16 + (l & 15);
#pragma unroll
  for (int mi = 0; mi < 4; mi++) {
    int row0 = p0 + mi * 16 + (l >> 4) * 4;
#pragma unroll
    for (int j = 0; j < 4; j++)
      Y[(size_t)(row0 + j) * ldy + col] = acc[mi][j];
  }
  int b = p0 >> 12;               // 64-row blocks never straddle batches
  float a1 = 0.f, a2 = 0.f;
#pragma unroll
  for (int mi = 0; mi < 4; mi++)
#pragma unroll
    for (int j = 0; j < 4; j++) {
      float y = acc[mi][j];
      a1 += y;
      a2 = fmaf(y, y, a2);
    }
  a1 += __shfl_xor(a1, 16); a2 += __shfl_xor(a2, 16);
  a1 += __shfl_xor(a1, 32); a2 += __shfl_xor(a2, 32);
  if ((l >> 4) == 0) {
    atomicAdd(&T1s[b * 128 + col], a1);
    atomicAdd(&T2s[b * 128 + col], a2);
  }
}

// Gather pass: u from bf16 Ub (coalesced), v from bf16 Vb rows.
// Writes S = u + maxV (bf16) — passB reads ONLY S.
template <int O>
__global__ void k_gather(const uint16_t* __restrict__ Ub,
                         const uint16_t* __restrict__ Vb,
                         const int* __restrict__ idx,
                         uint16_t* __restrict__ S,
                         float* __restrict__ T1, float* __restrict__ T2) {
  int L = blockIdx.x;             // 1024 blocks
  int rx = L & 7;
  int b = rx >> 1;
  int j = ((L >> 3) << 1) + (rx & 1);
  int n0 = j << 4;
  int o = threadIdx.x;
  float a1 = 0.f, a2 = 0.f;
  for (int pi = 0; pi < 16; pi++) {
    int row = b * 4096 + n0 + pi;
    float u = bf2f(Ub[(size_t)row * O + o]);
    float s1 = 0.f, s2 = 0.f, vmax = -1e30f;
#pragma unroll
    for (int jj = 0; jj < KNN; jj++) {
      int m = idx[row * 10 + jj];
      float v = bf2f(Vb[(size_t)(b * 4096 + m) * O + o]);
      s1 += v;
      float x = u + v;
      s2 = fmaf(x, x, s2);
      vmax = fmaxf(vmax, v);
    }
    S[(size_t)row * O + o] = f2bf(u + vmax);
    a1 += 10.f * u + s1;
    a2 += s2;
  }
  atomicAdd(&T1[b * O + o], a1);
  atomicAdd(&T2[b * O + o], a2);
}

// x = lrelu((S - mu) * rsqrt(var+eps)) -> Xcat[:, coff:coff+O] (bf16)
template <int O>
__global__ void k_passB(const uint16_t* __restrict__ S, int coff,
                        const float* __restrict__ T1, const float* __restrict__ T2,
                        uint16_t* __restrict__ Xcat) {
  int t = blockIdx.x * 256 + threadIdx.x;
  int o = t & (O - 1);
  int pn = t / O;
  int b = pn >> 12;
  float mu = T1[b * O + o] * (1.f / 40960.f);
  float e2 = T2[b * O + o] * (1.f / 40960.f);
  float inv = rsqrtf(e2 - mu * mu + 1e-5f);
  float x = (bf2f(S[(size_t)pn * O + o]) - mu) * inv;
  Xcat[pn * 512 + coff + o] = f2bf(x >= 0.f ? x : 0.2f * x);
}

// out[b][o][n] = lrelu((Y3[b][n][o]-mu)*inv)  (transposing write)
__global__ void k_out(const float* __restrict__ Y3, const float* __restrict__ T1,
                      const float* __restrict__ T2, float* __restrict__ out) {
  __shared__ float tile[32][33];
  int bid = blockIdx.x;           // 2048
  int b = bid >> 9;
  int r = bid & 511;
  int n0 = (r >> 2) << 5;
  int o0 = (r & 3) << 5;
  int tx = threadIdx.x & 31, ty = threadIdx.x >> 5;
  int o = o0 + tx;
  float mu = T1[b * 128 + o] * (1.f / 4096.f);
  float e2 = T2[b * 128 + o] * (1.f / 4096.f);
  float inv = rsqrtf(e2 - mu * mu + 1e-5f);
#pragma unroll
  for (int i = 0; i < 4; i++) {
    int n = n0 + ty + i * 8;
    float v = (Y3[(b * 4096 + n) * 128 + o] - mu) * inv;
    tile[ty + i * 8][tx] = v >= 0.f ? v : 0.2f * v;
  }
  __syncthreads();
#pragma unroll
  for (int i = 0; i < 4; i++) {
    int oo = o0 + ty + i * 8;
    out[(b * 128 + oo) * 4096 + n0 + tx] = tile[tx][ty + i * 8];
  }
}

extern "C" void kernel_launch(void* const* d_in, const int* in_sizes, int n_in,
                              void* d_out, int out_size, void* d_ws, size_t ws_size,
                              hipStream_t stream) {
  const float* coords   = (const float*)d_in[0];
  const float* features = (const float*)d_in[1];
  const float* W1       = (const float*)d_in[2];
  const float* W2       = (const float*)d_in[3];
  const float* W3       = (const float*)d_in[4];
  float* out = (float*)d_out;

  float*    ws    = (float*)d_ws;
  uint16_t* Xcat  = (uint16_t*)ws;                 // bf16 [4][4096][512]
  float*    candd = ws + 4194304;
  float*    tq    = ws + 5505024;
  float4*   pts4  = (float4*)(ws + 5521408);
  uint16_t* Ub1   = (uint16_t*)(ws + 5586944);
  uint16_t* Ub2   = (uint16_t*)(ws + 6635520);
  uint16_t* Sbuf  = (uint16_t*)(ws + 12582912);
  float*    Y3    = ws + 14680064;
  int*      idxb  = (int*)(ws + 16777216);
  uint16_t* W1cat = (uint16_t*)(ws + 16941056);
  uint16_t* W2cat = (uint16_t*)(ws + 16957440);
  uint16_t* W3b   = (uint16_t*)(ws + 16990208);
  float*    stats = ws + 17022976;
  uint16_t* Vb1   = (uint16_t*)(ws + 17031168);
  uint16_t* Vb2   = (uint16_t*)(ws + 18079744);

  k_prep<<<2784, 256, 0, stream>>>(W1, W2, W3, coords, features, Xcat,
                                   W1cat, W2cat, W3b, stats, pts4);
  k_knn_thr<<<512, 256, 0, stream>>>(pts4, candd);
  k_knn_merge<<<4096, 256, 0, stream>>>(candd, tq);
  k_knn_cf<<<2048, 256, 0, stream>>>(pts4, tq, idxb);

  // stage 1: [U|V] = Xcat[:,0:128] @ W1cat^T (O=256) -> Ub1/Vb1 bf16
  k_gemm_bf<<<dim3(128, 4), 256, 0, stream>>>(Xcat, 512, 0, W1cat, 128, 128,
                                              Ub1, Vb1, 128, 128, 128);
  k_gather<128><<<1024, 128, 0, stream>>>(Ub1, Vb1, idxb, Sbuf, stats + 0, stats + 512);
  k_passB<128><<<8192, 256, 0, stream>>>(Sbuf, 128, stats + 0, stats + 512, Xcat);

  // stage 2: [U|V] = Xcat[:,128:256] @ W2cat^T (O=512) -> Ub2/Vb2 bf16
  k_gemm_bf<<<dim3(128, 8), 256, 0, stream>>>(Xcat, 512, 128, W2cat, 128, 128,
                                              Ub2, Vb2, 256, 256, 256);
  k_gather<256><<<1024, 256, 0, stream>>>(Ub2, Vb2, idxb, Sbuf, stats + 1024, stats + 2048);
  k_passB<256><<<16384, 256, 0, stream>>>(Sbuf, 256, stats + 1024, stats + 2048, Xcat);

  // fuse: Y3 = Xcat[:, 0:512] @ W3b^T (O=128; BM=64, fused stats)
  k_gemm3<<<dim3(256, 2), 256, 0, stream>>>(Xcat, 512, W3b, 512, Y3, 128, 512,
                                            stats + 3072, stats + 3584);
  k_out<<<2048, 256, 0, stream>>>(Y3, stats + 3072, stats + 3584, out);
}

// Round 22
// 158.312 us; speedup vs baseline: 1.0104x; 1.0104x over previous
//
#include <hip/hip_runtime.h>
#include <math.h>
#include <stdint.h>

// Problem constants
#define NB 4
#define NC 128
#define NP 4096
#define KNN 10

// ---------------- ws layout (float-slot offsets) ----------------
// Xcat (bf16 u16) : [B][N][512]   @ 0         (16MB)
// KNN scratch     : @ 4194304  (candd 1310720, tq 16384, pts4 65536 slots)
// Ub1  (bf16 u16) : [B][N][128]   @ 5586944
// Ub2  (bf16 u16) : [B][N][256]   @ 6635520
// Sbuf (bf16 u16) : [B][N][256]   @ 12582912  (S = u + maxV)
// Y3   (f32)      : [B][N][128]   @ 14680064
// idx  (i32)      : [B][N][10]    @ 16777216
// W1cat (bf16)    : [256][128]    @ 16941056
// W2cat (bf16)    : [512][128]    @ 16957440
// W3b  (bf16)     : [128][512]    @ 16990208
// stats (f32)     : [8192]        @ 17022976
// Vb1  (bf16 u16) : [B][N][128]   @ 17031168
// Vb2  (bf16 u16) : [B][N][256]   @ 18079744

__device__ __forceinline__ uint16_t f2bf(float f) {
  uint32_t u = __float_as_uint(f);
  u += 0x7fffu + ((u >> 16) & 1u);      // RNE
  return (uint16_t)(u >> 16);
}
__device__ __forceinline__ float bf2f(uint16_t h) {
  return __uint_as_float(((uint32_t)h) << 16);
}

__device__ __forceinline__ void async16(const void* g, void* l) {
  __builtin_amdgcn_global_load_lds(
      (const __attribute__((address_space(1))) unsigned int*)g,
      (__attribute__((address_space(3))) unsigned int*)l,
      16, 0, 0);
}

// float -> order-preserving uint32 (all finite values)
__device__ __forceinline__ uint32_t fsort(float f) {
  uint32_t u = __float_as_uint(f);
  return (u & 0x80000000u) ? ~u : (u | 0x80000000u);
}
__device__ __forceinline__ float funsort(uint32_t k) {
  uint32_t u = (k & 0x80000000u) ? (k & 0x7fffffffu) : ~k;
  return __uint_as_float(u);
}

typedef __bf16 bf16x8 __attribute__((ext_vector_type(8)));
typedef float f32x4 __attribute__((ext_vector_type(4)));

// prep (blocks >= 2048) + feature transpose (blocks 0..2047), fused.
__global__ void k_prep(const float* __restrict__ W1, const float* __restrict__ W2,
                       const float* __restrict__ W3, const float* __restrict__ coords,
                       const float* __restrict__ feat,
                       uint16_t* __restrict__ Xcat,
                       uint16_t* __restrict__ W1cat, uint16_t* __restrict__ W2cat,
                       uint16_t* __restrict__ W3b,
                       float* __restrict__ stats, float4* __restrict__ pts4) {
  __shared__ float tile[32][33];
  int bid = blockIdx.x;
  if (bid < 2048) {               // transpose: feat [B][128][4096] -> Xcat bf16
    int b = bid >> 9;
    int r = bid & 511;
    int n0 = (r >> 2) << 5;
    int c0 = (r & 3) << 5;
    int tx = threadIdx.x & 31, ty = threadIdx.x >> 5;
#pragma unroll
    for (int i = 0; i < 4; i++) {
      int c = c0 + ty + i * 8;
      tile[ty + i * 8][tx] = feat[(b * 128 + c) * 4096 + n0 + tx];
    }
    __syncthreads();
#pragma unroll
    for (int i = 0; i < 4; i++) {
      int n = n0 + ty + i * 8;
      Xcat[((b * 4096 + n) * 512) + c0 + tx] = f2bf(tile[tx][ty + i * 8]);
    }
    return;
  }
  int t = (bid - 2048) * 256 + threadIdx.x;
  if (t < 32768) {
    int o = t >> 7, c = t & 127;
    float v;
    if (o < 128) v = W1[o * 256 + c] - W1[o * 256 + 128 + c];     // A1 = W1a - W1b
    else         v = W1[(o - 128) * 256 + 128 + c];               // B1 = W1b
    W1cat[t] = f2bf(v);
  } else if (t < 98304) {
    int t2 = t - 32768;
    int o = t2 >> 7, c = t2 & 127;
    float v;
    if (o < 256) v = W2[o * 256 + c] - W2[o * 256 + 128 + c];     // A2
    else         v = W2[(o - 256) * 256 + 128 + c];               // B2
    W2cat[t2] = f2bf(v);
  } else if (t < 163840) {
    int t2 = t - 98304;
    W3b[t2] = f2bf(W3[t2]);
  } else if (t < 163840 + 8192) {
    stats[t - 163840] = 0.f;
  } else if (t < 163840 + 8192 + 16384) {
    int t2 = t - 163840 - 8192;
    int b = t2 >> 12, n = t2 & 4095;
    const float* cb = coords + b * 12288;
    float x = cb[n], y = cb[4096 + n], z = cb[8192 + n];
    float w = fmaf(x, x, fmaf(y, y, z * z));
    pts4[t2] = make_float4(x, y, z, w);
  }
}

// ---------------- KNN: exact subsampled-threshold scheme ----------------
// d = fmaf(-2, dot, q.w + p.w), dot = fmaf(qx,px, fmaf(qy,py, qz*pz)):
// SAME chain in thr and in cf's selection recompute (bit-identical).
__global__ void k_knn_thr(const float4* __restrict__ pts4, float* __restrict__ candd) {
  int L = blockIdx.x;             // 512 = b(4) x qb(16) x ch(8)
  int ch = L & 7;
  int qb = (L >> 3) & 15;
  int b = L >> 7;
  int m0 = ch << 7;               // subset points ch*128 .. +127  (all < 1024)
  const float4* pb = pts4 + b * 4096;
  int t = threadIdx.x;
  int q = (qb << 8) + t;
  float4 qp = pb[q];
  float d10[10];
#pragma unroll
  for (int i = 0; i < 10; i++) d10[i] = 1e30f;
#pragma unroll 2
  for (int mm = 0; mm < 128; mm++) {
    int m = m0 + mm;
    float4 p = pb[m];                     // wave-uniform -> broadcast
    float dot = fmaf(qp.x, p.x, fmaf(qp.y, p.y, qp.z * p.z));
    float s = qp.w + p.w;
    float d = fmaf(-2.f, dot, s);
    d = (m == q) ? 1e30f : d;             // self-exclusion
    if (d < d10[9]) {
      float carry = d;
#pragma unroll
      for (int i = 0; i < 10; i++) {
        float lo = fminf(d10[i], carry);
        carry = fmaxf(d10[i], carry);
        d10[i] = lo;
      }
    }
  }
  int row = b * 4096 + q;
#pragma unroll
  for (int i = 0; i < 10; i++) candd[row * 80 + ch * 10 + i] = d10[i];
}

__global__ void k_knn_merge(const float* __restrict__ candd, float* __restrict__ tq) {
  int gw = blockIdx.x * 4 + (threadIdx.x >> 6);   // 4096 blocks -> 16384 waves
  int l = threadIdx.x & 63;
  const float* cp = candd + (size_t)gw * 80;
  uint32_t k0 = fsort(cp[l]);
  uint32_t k1 = (l < 16) ? fsort(cp[64 + l]) : 0xFFFFFFFFu;
  uint32_t g = 0;
#pragma unroll
  for (int it = 0; it < 10; it++) {
    uint32_t m = k0 < k1 ? k0 : k1;
#pragma unroll
    for (int s = 1; s < 64; s <<= 1) {
      uint32_t o = __shfl_xor(m, s);
      m = o < m ? o : m;
    }
    g = m;
    if (it < 9) {
      if (k0 == m) k0 = 0xFFFFFFFFu;
      else if (k1 == m) k1 = 0xFFFFFFFFu;
    }
  }
  if (l == 0) tq[gw] = funsort(g);
}

// Phase C+D fused: register-query/partitioned-point scan with 512 threads
// (8 waves) per block: per-thread load chain halves (8 points) and wave
// count doubles vs r20 — attacks the measured issue-gap (VALUBusy 49%).
// Selection = r20's proven u64 path, 1 query per wave.
#define CFCAP 112
#define DMARGIN 1e-3f
__global__ __launch_bounds__(512) void k_knn_cf(
    const float4* __restrict__ pts4, const float* __restrict__ tq,
    int* __restrict__ idxout) {
  __shared__ int candi[8 * CFCAP];           // 3.5 KB
  __shared__ int ccnt[8];
  int blk = blockIdx.x;           // 2048 = b(4) x qg(512)
  int b = blk >> 9;
  int qg = blk & 511;
  int t = threadIdx.x;            // 0..511
  if (t < 8) ccnt[t] = 0;
  const float4* pb = pts4 + b * 4096;
  int qbase = qg * 8;
  float q2x[8], q2y[8], q2z[8], rhs[8];
#pragma unroll
  for (int j = 0; j < 8; j++) {
    float4 qp = pb[qbase + j];
    q2x[j] = -2.f * qp.x; q2y[j] = -2.f * qp.y; q2z[j] = -2.f * qp.z;
    rhs[j] = tq[b * 4096 + qbase + j] + DMARGIN - qp.w;
  }
  __syncthreads();                // ccnt init visible
#pragma unroll 4
  for (int c = 0; c < 8; c++) {
    float4 p = pb[c * 512 + t];   // coalesced global (L2-resident)
    int m = c * 512 + t;
#pragma unroll
    for (int j = 0; j < 8; j++) {
      float tt = fmaf(q2x[j], p.x, fmaf(q2y[j], p.y, fmaf(q2z[j], p.z, p.w)));
      if (tt <= rhs[j]) {
        int pos = atomicAdd(&ccnt[j], 1);
        if (pos < CFCAP) candi[j * CFCAP + pos] = m;
      }
    }
  }
  __syncthreads();
  // selection: 8 waves; wave w handles query w. Exact d recompute
  // (bit-identical chain vs thr) + u64 (d,idx) lexicographic top-10.
  int w = t >> 6;
  int l = t & 63;
  {
    int qloc = w;
    int q2 = qbase + qloc;
    float4 qp2 = pb[q2];
    int c = ccnt[qloc]; c = c < CFCAP ? c : CFCAP;
    unsigned long long k0 = ~0ULL, k1 = ~0ULL;
#pragma unroll
    for (int u = 0; u < 2; u++) {
      int j = u * 64 + l;
      if (j < c) {
        int m = candi[qloc * CFCAP + j];
        float4 p = pb[m];
        float dot = fmaf(qp2.x, p.x, fmaf(qp2.y, p.y, qp2.z * p.z));
        float s = qp2.w + p.w;
        float d = fmaf(-2.f, dot, s);        // EXACT, bit-identical to thr
        d = (m == q2) ? 1e30f : d;           // self-exclusion
        unsigned long long key = (((unsigned long long)fsort(d)) << 32) | (uint32_t)m;
        if (u == 0) k0 = key; else k1 = key;
      }
    }
    uint32_t keep[10];
#pragma unroll
    for (int it = 0; it < 10; it++) {
      unsigned long long m = k0 < k1 ? k0 : k1;
#pragma unroll
      for (int s = 1; s < 64; s <<= 1) {
        unsigned long long o = __shfl_xor(m, s);
        m = o < m ? o : m;
      }
      keep[it] = (uint32_t)(m & 0xffffffffu);
      if (k0 == m) k0 = ~0ULL;
      else if (k1 == m) k1 = ~0ULL;
    }
    if (l == 0) {
      int orow = b * 4096 + q2;
#pragma unroll
      for (int i = 0; i < 10; i++) idxout[orow * 10 + i] = (int)keep[i];
    }
  }
}

// ---------------- bf16 MFMA GEMM (stage 1/2): BM=128, BN=64 ----------------
// [U|V] = X @ W^T; U blocks -> Ub bf16, V blocks -> Vb bf16.
__global__ __launch_bounds__(256) void k_gemm_bf(
    const uint16_t* __restrict__ Xb, int ldx, int xoff,
    const uint16_t* __restrict__ Wb, int ldw, int K,
    uint16_t* __restrict__ Ub, uint16_t* __restrict__ Vb,
    int voff, int uld, int vld) {
  __shared__ __align__(16) uint8_t lds[49152];
  const int t = threadIdx.x;
  const int l = t & 63;
  const int wid = t >> 6;
  const int wr = wid & 1, wc = wid >> 1;
  const int p0 = blockIdx.x * 128;
  const int o0 = blockIdx.y * 64;

  const int rA = l >> 3;
  const int cbp = ((l & 7) ^ rA) << 4;
  const int swl = (l & 7) << 4;

  f32x4 acc[4][2];
#pragma unroll
  for (int mi = 0; mi < 4; mi++)
#pragma unroll
    for (int ni = 0; ni < 2; ni++) acc[mi][ni] = (f32x4)0.f;

  auto stage = [&](int k0, int buf) {
    const uint16_t* Xs_ = Xb + (size_t)p0 * ldx + xoff + k0;
    const uint16_t* Ws_ = Wb + (size_t)o0 * ldw + k0;
#pragma unroll
    for (int cc = 0; cc < 4; cc++) {
      int c = wid * 4 + cc;
      const uint8_t* g = (const uint8_t*)(Xs_ + (size_t)(c * 8 + rA) * ldx) + cbp;
      async16(g, &lds[buf * 16384 + c * 1024]);
    }
#pragma unroll
    for (int cc = 0; cc < 2; cc++) {
      int c = wid * 2 + cc;
      const uint8_t* g = (const uint8_t*)(Ws_ + (size_t)(c * 8 + rA) * ldw) + cbp;
      async16(g, &lds[32768 + buf * 8192 + c * 1024]);
    }
  };

  auto compute = [&](int buf) {
    const uint8_t* Ab = &lds[buf * 16384];
    const uint8_t* Bb = &lds[32768 + buf * 8192];
#pragma unroll
    for (int ks = 0; ks < 2; ks++) {
      int cb = ks * 64 + ((l >> 4) << 4);
      bf16x8 bfr[2];
#pragma unroll
      for (int ni = 0; ni < 2; ni++) {
        int n = wc * 32 + ni * 16 + (l & 15);
        bfr[ni] = *(const bf16x8*)(Bb + n * 128 + (cb ^ swl));
      }
#pragma unroll
      for (int mi = 0; mi < 4; mi++) {
        int m = wr * 64 + mi * 16 + (l & 15);
        bf16x8 afr = *(const bf16x8*)(Ab + m * 128 + (cb ^ swl));
        acc[mi][0] = __builtin_amdgcn_mfma_f32_16x16x32_bf16(afr, bfr[0], acc[mi][0], 0, 0, 0);
        acc[mi][1] = __builtin_amdgcn_mfma_f32_16x16x32_bf16(afr, bfr[1], acc[mi][1], 0, 0, 0);
      }
    }
  };

  const int nsteps = K >> 6;
  stage(0, 0);
  for (int s = 0; s < nsteps; s++) {
    __syncthreads();
    if (s + 1 < nsteps) stage((s + 1) << 6, (s + 1) & 1);
    compute(s & 1);
  }

  const bool isv = (o0 >= voff);  // wave-uniform
#pragma unroll
  for (int mi = 0; mi < 4; mi++)
#pragma unroll
    for (int ni = 0; ni < 2; ni++) {
      int col = o0 + wc * 32 + ni * 16 + (l & 15);
      int row0 = p0 + wr * 64 + mi * 16 + (l >> 4) * 4;
#pragma unroll
      for (int j = 0; j < 4; j++) {
        if (isv) Vb[(size_t)(row0 + j) * vld + (col - voff)] = f2bf(acc[mi][ni][j]);
        else     Ub[(size_t)(row0 + j) * uld + col] = f2bf(acc[mi][ni][j]);
      }
    }
}

// ---------------- gemm3: BM=64, BN=64, f32 out + fused stats ----------------
__global__ __launch_bounds__(256) void k_gemm3(
    const uint16_t* __restrict__ Xb, int ldx,
    const uint16_t* __restrict__ Wb, int ldw,
    float* __restrict__ Y, int ldy, int K,
    float* __restrict__ T1s, float* __restrict__ T2s) {
  __shared__ __align__(16) uint8_t lds[32768];
  const int t = threadIdx.x;
  const int l = t & 63;
  const int wid = t >> 6;         // wc 0..3
  const int p0 = blockIdx.x * 64;
  const int o0 = blockIdx.y * 64;

  const int rA = l >> 3;
  const int cbp = ((l & 7) ^ rA) << 4;
  const int swl = (l & 7) << 4;

  f32x4 acc[4];
#pragma unroll
  for (int mi = 0; mi < 4; mi++) acc[mi] = (f32x4)0.f;

  auto stage = [&](int k0, int buf) {
    const uint16_t* Xs_ = Xb + (size_t)p0 * ldx + k0;
    const uint16_t* Ws_ = Wb + (size_t)o0 * ldw + k0;
#pragma unroll
    for (int cc = 0; cc < 2; cc++) {
      int c = wid * 2 + cc;
      const uint8_t* g = (const uint8_t*)(Xs_ + (size_t)(c * 8 + rA) * ldx) + cbp;
      async16(g, &lds[buf * 16384 + c * 1024]);
    }
#pragma unroll
    for (int cc = 0; cc < 2; cc++) {
      int c = wid * 2 + cc;
      const uint8_t* g = (const uint8_t*)(Ws_ + (size_t)(c * 8 + rA) * ldw) + cbp;
      async16(g, &lds[buf * 16384 + 8192 + c * 1024]);
    }
  };

  auto compute = [&](int buf) {
    const uint8_t* Ab = &lds[buf * 16384];
    const uint8_t* Bb = &lds[buf * 16384 + 8192];
#pragma unroll
    for (int ks = 0; ks < 2; ks++) {
      int cb = ks * 64 + ((l >> 4) << 4);
      int n = wid * 16 + (l & 15);
      bf16x8 bfr = *(const bf16x8*)(Bb + n * 128 + (cb ^ swl));
#pragma unroll
      for (int mi = 0; mi < 4; mi++) {
        int m = mi * 16 + (l & 15);
        bf16x8 afr = *(const bf16x8*)(Ab + m * 128 + (cb ^ swl));
        acc[mi] = __builtin_amdgcn_mfma_f32_16x16x32_bf16(afr, bfr, acc[mi], 0, 0, 0);
      }
    }
  };

  const int nsteps = K >> 6;      // 8
  stage(0, 0);
  for (int s = 0; s < nsteps; s++) {
    __syncthreads();
    if (s + 1 < nsteps) stage((s + 1) << 6, (s + 1) & 1);
    compute(s & 1);
  }

  int col = o0 + wid * 16 + (l & 15);
#pragma unroll
  for (int mi = 0; mi < 4; mi++) {
    int row0 = p0 + mi * 16 + (l >> 4) * 4;
#pragma unroll
    for (int j = 0; j < 4; j++)
      Y[(size_t)(row0 + j) * ldy + col] = acc[mi][j];
  }
  int b = p0 >> 12;               // 64-row blocks never straddle batches
  float a1 = 0.f, a2 = 0.f;
#pragma unroll
  for (int mi = 0; mi < 4; mi++)
#pragma unroll
    for (int j = 0; j < 4; j++) {
      float y = acc[mi][j];
      a1 += y;
      a2 = fmaf(y, y, a2);
    }
  a1 += __shfl_xor(a1, 16); a2 += __shfl_xor(a2, 16);
  a1 += __shfl_xor(a1, 32); a2 += __shfl_xor(a2, 32);
  if ((l >> 4) == 0) {
    atomicAdd(&T1s[b * 128 + col], a1);
    atomicAdd(&T2s[b * 128 + col], a2);
  }
}

// Gather pass: u from bf16 Ub (coalesced), v from bf16 Vb rows.
// Writes S = u + maxV (bf16) — passB reads ONLY S.
template <int O>
__global__ void k_gather(const uint16_t* __restrict__ Ub,
                         const uint16_t* __restrict__ Vb,
                         const int* __restrict__ idx,
                         uint16_t* __restrict__ S,
                         float* __restrict__ T1, float* __restrict__ T2) {
  int L = blockIdx.x;             // 1024 blocks
  int rx = L & 7;
  int b = rx >> 1;
  int j = ((L >> 3) << 1) + (rx & 1);
  int n0 = j << 4;
  int o = threadIdx.x;
  float a1 = 0.f, a2 = 0.f;
  for (int pi = 0; pi < 16; pi++) {
    int row = b * 4096 + n0 + pi;
    float u = bf2f(Ub[(size_t)row * O + o]);
    float s1 = 0.f, s2 = 0.f, vmax = -1e30f;
#pragma unroll
    for (int jj = 0; jj < KNN; jj++) {
      int m = idx[row * 10 + jj];
      float v = bf2f(Vb[(size_t)(b * 4096 + m) * O + o]);
      s1 += v;
      float x = u + v;
      s2 = fmaf(x, x, s2);
      vmax = fmaxf(vmax, v);
    }
    S[(size_t)row * O + o] = f2bf(u + vmax);
    a1 += 10.f * u + s1;
    a2 += s2;
  }
  atomicAdd(&T1[b * O + o], a1);
  atomicAdd(&T2[b * O + o], a2);
}

// x = lrelu((S - mu) * rsqrt(var+eps)) -> Xcat[:, coff:coff+O] (bf16)
template <int O>
__global__ void k_passB(const uint16_t* __restrict__ S, int coff,
                        const float* __restrict__ T1, const float* __restrict__ T2,
                        uint16_t* __restrict__ Xcat) {
  int t = blockIdx.x * 256 + threadIdx.x;
  int o = t & (O - 1);
  int pn = t / O;
  int b = pn >> 12;
  float mu = T1[b * O + o] * (1.f / 40960.f);
  float e2 = T2[b * O + o] * (1.f / 40960.f);
  float inv = rsqrtf(e2 - mu * mu + 1e-5f);
  float x = (bf2f(S[(size_t)pn * O + o]) - mu) * inv;
  Xcat[pn * 512 + coff + o] = f2bf(x >= 0.f ? x : 0.2f * x);
}

// out[b][o][n] = lrelu((Y3[b][n][o]-mu)*inv)  (transposing write)
__global__ void k_out(const float* __restrict__ Y3, const float* __restrict__ T1,
                      const float* __restrict__ T2, float* __restrict__ out) {
  __shared__ float tile[32][33];
  int bid = blockIdx.x;           // 2048
  int b = bid >> 9;
  int r = bid & 511;
  int n0 = (r >> 2) << 5;
  int o0 = (r & 3) << 5;
  int tx = threadIdx.x & 31, ty = threadIdx.x >> 5;
  int o = o0 + tx;
  float mu = T1[b * 128 + o] * (1.f / 4096.f);
  float e2 = T2[b * 128 + o] * (1.f / 4096.f);
  float inv = rsqrtf(e2 - mu * mu + 1e-5f);
#pragma unroll
  for (int i = 0; i < 4; i++) {
    int n = n0 + ty + i * 8;
    float v = (Y3[(b * 4096 + n) * 128 + o] - mu) * inv;
    tile[ty + i * 8][tx] = v >= 0.f ? v : 0.2f * v;
  }
  __syncthreads();
#pragma unroll
  for (int i = 0; i < 4; i++) {
    int oo = o0 + ty + i * 8;
    out[(b * 128 + oo) * 4096 + n0 + tx] = tile[tx][ty + i * 8];
  }
}

extern "C" void kernel_launch(void* const* d_in, const int* in_sizes, int n_in,
                              void* d_out, int out_size, void* d_ws, size_t ws_size,
                              hipStream_t stream) {
  const float* coords   = (const float*)d_in[0];
  const float* features = (const float*)d_in[1];
  const float* W1       = (const float*)d_in[2];
  const float* W2       = (const float*)d_in[3];
  const float* W3       = (const float*)d_in[4];
  float* out = (float*)d_out;

  float*    ws    = (float*)d_ws;
  uint16_t* Xcat  = (uint16_t*)ws;                 // bf16 [4][4096][512]
  float*    candd = ws + 4194304;
  float*    tq    = ws + 5505024;
  float4*   pts4  = (float4*)(ws + 5521408);
  uint16_t* Ub1   = (uint16_t*)(ws + 5586944);
  uint16_t* Ub2   = (uint16_t*)(ws + 6635520);
  uint16_t* Sbuf  = (uint16_t*)(ws + 12582912);
  float*    Y3    = ws + 14680064;
  int*      idxb  = (int*)(ws + 16777216);
  uint16_t* W1cat = (uint16_t*)(ws + 16941056);
  uint16_t* W2cat = (uint16_t*)(ws + 16957440);
  uint16_t* W3b   = (uint16_t*)(ws + 16990208);
  float*    stats = ws + 17022976;
  uint16_t* Vb1   = (uint16_t*)(ws + 17031168);
  uint16_t* Vb2   = (uint16_t*)(ws + 18079744);

  k_prep<<<2784, 256, 0, stream>>>(W1, W2, W3, coords, features, Xcat,
                                   W1cat, W2cat, W3b, stats, pts4);
  k_knn_thr<<<512, 256, 0, stream>>>(pts4, candd);
  k_knn_merge<<<4096, 256, 0, stream>>>(candd, tq);
  k_knn_cf<<<2048, 512, 0, stream>>>(pts4, tq, idxb);

  // stage 1: [U|V] = Xcat[:,0:128] @ W1cat^T (O=256) -> Ub1/Vb1 bf16
  k_gemm_bf<<<dim3(128, 4), 256, 0, stream>>>(Xcat, 512, 0, W1cat, 128, 128,
                                              Ub1, Vb1, 128, 128, 128);
  k_gather<128><<<1024, 128, 0, stream>>>(Ub1, Vb1, idxb, Sbuf, stats + 0, stats + 512);
  k_passB<128><<<8192, 256, 0, stream>>>(Sbuf, 128, stats + 0, stats + 512, Xcat);

  // stage 2: [U|V] = Xcat[:,128:256] @ W2cat^T (O=512) -> Ub2/Vb2 bf16
  k_gemm_bf<<<dim3(128, 8), 256, 0, stream>>>(Xcat, 512, 128, W2cat, 128, 128,
                                              Ub2, Vb2, 256, 256, 256);
  k_gather<256><<<1024, 256, 0, stream>>>(Ub2, Vb2, idxb, Sbuf, stats + 1024, stats + 2048);
  k_passB<256><<<16384, 256, 0, stream>>>(Sbuf, 256, stats + 1024, stats + 2048, Xcat);

  // fuse: Y3 = Xcat[:, 0:512] @ W3b^T (O=128; BM=64, fused stats)
  k_gemm3<<<dim3(256, 2), 256, 0, stream>>>(Xcat, 512, W3b, 512, Y3, 128, 512,
                                            stats + 3072, stats + 3584);
  k_out<<<2048, 256, 0, stream>>>(Y3, stats + 3072, stats + 3584, out);
}